// Round 2
// baseline (115.611 us; speedup 1.0000x reference)
//
#include <hip/hip_runtime.h>
#include <hip/hip_bf16.h>

typedef __attribute__((ext_vector_type(4))) float f32x4;
typedef __attribute__((ext_vector_type(8))) short s16x8;
typedef __attribute__((ext_vector_type(4))) unsigned int u32x4;

// Problem constants: B*R*C = 3136 positions, n_caps=10, n_in=64, d_in=16, d_out=16.
// inputs: [3136][64][16] f32, W: [10][64][16][16] f32, out: [3136][10][16] f32.
//
// Gram-space routing: per (pos,n): R[i,o] (64x16); G = R^T R (16x16, MFMA);
// s0 = (1/64) R^T 1 (MFMA with ones-A); s_{t+1} = s_t + G squash(s_t); out=squash(s2).

__global__ __launch_bounds__(256) void caps_routing_kernel(
    const float* __restrict__ inp,
    const float* __restrict__ W,
    float* __restrict__ out)
{
    const int tid  = threadIdx.x;
    const int wid  = tid >> 6;
    const int lane = tid & 63;
    const int g    = blockIdx.x * 4 + wid;   // global wave id: 0..7839
    const int quad = g / 10;                 // position quad: 0..783
    const int n    = g - quad * 10;          // capsule n: 0..9
    const int pos0 = quad * 4;

    // per-wave bf16 res buffer: 64 rows x 16 cols (2 KB/wave)
    __shared__ __align__(16) unsigned short res_lds[4][64 * 16];
    unsigned short* myres = res_lds[wid];

    // ---------------- einsum: r[p][o] = sum_e inp[pos,i=lane,e] * W[n,i=lane,e,o]
    f32x4 r[4][4];
#pragma unroll
    for (int p = 0; p < 4; ++p)
#pragma unroll
        for (int q = 0; q < 4; ++q)
            r[p][q] = (f32x4)0.0f;

    const float* wbase = W + (size_t)((n * 64 + lane) * 16) * 16;
    const float* abase = inp + (size_t)pos0 * 1024 + lane * 16;

    // e-loop split into 4 blocks of 4; inp loaded as f32x4 (full 64B line per
    // lane per pos per block -> no scalar-stride over-fetch into L3)
#pragma unroll
    for (int eb = 0; eb < 4; ++eb) {
        f32x4 a0 = *(const f32x4*)(abase + 0 * 1024 + eb * 4);
        f32x4 a1 = *(const f32x4*)(abase + 1 * 1024 + eb * 4);
        f32x4 a2 = *(const f32x4*)(abase + 2 * 1024 + eb * 4);
        f32x4 a3 = *(const f32x4*)(abase + 3 * 1024 + eb * 4);
#pragma unroll
        for (int j = 0; j < 4; ++j) {
            const int e = eb * 4 + j;
            f32x4 w0 = *(const f32x4*)(wbase + e * 16 + 0);
            f32x4 w1 = *(const f32x4*)(wbase + e * 16 + 4);
            f32x4 w2 = *(const f32x4*)(wbase + e * 16 + 8);
            f32x4 w3 = *(const f32x4*)(wbase + e * 16 + 12);
            r[0][0] += a0[j] * w0; r[0][1] += a0[j] * w1; r[0][2] += a0[j] * w2; r[0][3] += a0[j] * w3;
            r[1][0] += a1[j] * w0; r[1][1] += a1[j] * w1; r[1][2] += a1[j] * w2; r[1][3] += a1[j] * w3;
            r[2][0] += a2[j] * w0; r[2][1] += a2[j] * w1; r[2][2] += a2[j] * w2; r[2][3] += a2[j] * w3;
            r[3][0] += a3[j] * w0; r[3][1] += a3[j] * w1; r[3][2] += a3[j] * w2; r[3][3] += a3[j] * w3;
        }
    }

    const int col = lane & 15;
    const int kg  = lane >> 4;

    s16x8 ones;
#pragma unroll
    for (int j = 0; j < 8; ++j) ones[j] = (short)0x3F80;  // bf16 1.0

#pragma unroll
    for (int p = 0; p < 4; ++p) {
        // ---- pack r[p] (fp32) to bf16 row, store row i=lane to LDS
        unsigned int u[8];
#pragma unroll
        for (int q = 0; q < 4; ++q) {
            __hip_bfloat16 b0 = __float2bfloat16(r[p][q][0]);
            __hip_bfloat16 b1 = __float2bfloat16(r[p][q][1]);
            __hip_bfloat16 b2 = __float2bfloat16(r[p][q][2]);
            __hip_bfloat16 b3 = __float2bfloat16(r[p][q][3]);
            unsigned short s0 = *(unsigned short*)&b0;
            unsigned short s1 = *(unsigned short*)&b1;
            unsigned short s2 = *(unsigned short*)&b2;
            unsigned short s3 = *(unsigned short*)&b3;
            u[q * 2 + 0] = (unsigned int)s0 | ((unsigned int)s1 << 16);
            u[q * 2 + 1] = (unsigned int)s2 | ((unsigned int)s3 << 16);
        }
        u32x4* dst = (u32x4*)myres + lane * 2;
        dst[0] = (u32x4){u[0], u[1], u[2], u[3]};
        dst[1] = (u32x4){u[4], u[5], u[6], u[7]};

        // ---- read MFMA fragments: lane l holds res[c*32 + kg*8 + j][col]
        // (A-frag of R^T and B-frag of R have identical register contents)
        s16x8 fr0, fr1;
#pragma unroll
        for (int j = 0; j < 8; ++j)
            fr0[j] = (short)myres[(0 * 32 + kg * 8 + j) * 16 + col];
#pragma unroll
        for (int j = 0; j < 8; ++j)
            fr1[j] = (short)myres[(1 * 32 + kg * 8 + j) * 16 + col];

        f32x4 G  = (f32x4)0.0f;
        f32x4 C2 = (f32x4)0.0f;
        G  = __builtin_amdgcn_mfma_f32_16x16x32_bf16(fr0, fr0, G, 0, 0, 0);
        G  = __builtin_amdgcn_mfma_f32_16x16x32_bf16(fr1, fr1, G, 0, 0, 0);
        C2 = __builtin_amdgcn_mfma_f32_16x16x32_bf16(ones, fr0, C2, 0, 0, 0);
        C2 = __builtin_amdgcn_mfma_f32_16x16x32_bf16(ones, fr1, C2, 0, 0, 0);
        // G frag: reg rr holds G[row = kg*4+rr][col];  C2: colsum (all rows equal)

        float s = C2[0] * (1.0f / 64.0f);   // s0[col]

#pragma unroll
        for (int t = 0; t < 2; ++t) {
            float sn = s * s;
            sn += __shfl_xor(sn, 1);
            sn += __shfl_xor(sn, 2);
            sn += __shfl_xor(sn, 4);
            sn += __shfl_xor(sn, 8);            // sn = sum_o s[o]^2
            float scale = sqrtf(sn) / (1.0f + sn);
            float v = scale * s;                // v[col] = squash(s)[col]
            // gather v[o'] for o' = kg*4 + rr (lanes 0..15 hold v[o=lane])
            float v0 = __shfl(v, kg * 4 + 0);
            float v1 = __shfl(v, kg * 4 + 1);
            float v2 = __shfl(v, kg * 4 + 2);
            float v3 = __shfl(v, kg * 4 + 3);
            // (G v)[col] via symmetry: sum over rows o' of column col
            float acc = G[0] * v0 + G[1] * v1 + G[2] * v2 + G[3] * v3;
            acc += __shfl_xor(acc, 16);
            acc += __shfl_xor(acc, 32);
            s += acc;
        }

        float sn = s * s;
        sn += __shfl_xor(sn, 1);
        sn += __shfl_xor(sn, 2);
        sn += __shfl_xor(sn, 4);
        sn += __shfl_xor(sn, 8);
        float scale = sqrtf(sn) / (1.0f + sn);
        float v = scale * s;

        if (lane < 16)
            out[(size_t)((pos0 + p) * 10 + n) * 16 + lane] = v;
    }
}

extern "C" void kernel_launch(void* const* d_in, const int* in_sizes, int n_in,
                              void* d_out, int out_size, void* d_ws, size_t ws_size,
                              hipStream_t stream) {
    const float* inp = (const float*)d_in[0];   // [3136][64][16]
    const float* W   = (const float*)d_in[1];   // [10][64][16][16]
    float* out = (float*)d_out;                 // [3136][10][16]

    // 3136 positions / 4 per wave * 10 n = 7840 waves = 1960 blocks of 4 waves
    dim3 grid(1960), block(256);
    hipLaunchKernelGGL(caps_routing_kernel, grid, block, 0, stream, inp, W, out);
}

// Round 3
// 45.150 us; speedup vs baseline: 2.5606x; 2.5606x over previous
//
#include <hip/hip_runtime.h>
#include <hip/hip_bf16.h>

typedef __attribute__((ext_vector_type(4))) float f32x4;
typedef __attribute__((ext_vector_type(8))) short s16x8;

// B*R*C = 3136 positions, n_caps=10, n_in=64, d_in=16, caps_dim=16.
// inputs: [3136][64][16] f32, W: [10][64][16][16] f32 (16384 f32 per n),
// out: [3136][10][16] f32.
//
// Block = (n, 8 quads of 4 positions), 256 thr = 4 waves.
// Lane (w,l): i = w*16 + (l>>2)  (input capsule), oq = l&3 (o-quad).
// W[n] staged coalesced -> LDS (two 32KB halves) -> 64 persistent VGPRs/lane.
// Per quad: inp staged coalesced -> LDS (swizzled); f32 VALU einsum;
// res (bf16) -> LDS [p][o][i] (i fastest, chunk-XOR swizzle) so phase-B
// MFMA fragments are single ds_read_b128. Gram-space routing as before:
// G = R^T R, s0 = (1/64) R^T 1, s += G*squash(s) x2, out = squash(s).

#define QPB 8

__global__ __launch_bounds__(256, 3) void caps_kernel(
    const float* __restrict__ inp,
    const float* __restrict__ W,
    float* __restrict__ out)
{
    const int tid = threadIdx.x;
    const int w   = tid >> 6;
    const int l   = tid & 63;
    const int n   = blockIdx.x / 98;
    const int qg  = blockIdx.x % 98;

    extern __shared__ __align__(16) char smem[];
    float* W_s   = (float*)smem;                              // 32 KB (W half), prologue only
    float* inp_s = (float*)smem;                              // 16 KB (quad), main loop
    char*  res_s = smem + 16384;                              // 8 KB bf16 res

    const int i_ = w * 16 + (l >> 2);   // lane's input capsule i (0..63)
    const int oq = l & 3;               // lane's o-quad (o = oq*4..+3)

    // ---------------- prologue: stage W[n] halves coalesced, gather to regs
    f32x4 w_regs[16];  // W[i_, e, oq*4..+3] for e=0..15
    const float* Wn = W + (size_t)n * 16384;

#pragma unroll
    for (int k = 0; k < 8; ++k) {                 // half A: i 0..31 (2048 chunks)
        int g = k * 256 + tid;
        int i = g >> 6, c = g & 63;
        *(f32x4*)(W_s + i * 256 + ((c ^ (i & 7)) << 2)) = *(const f32x4*)(Wn + g * 4);
    }
    __syncthreads();
    if (w < 2) {
#pragma unroll
        for (int e = 0; e < 16; ++e)
            w_regs[e] = *(const f32x4*)(W_s + i_ * 256 + (((e * 4 + oq) ^ (i_ & 7)) << 2));
    }
    __syncthreads();
#pragma unroll
    for (int k = 0; k < 8; ++k) {                 // half B: i 32..63
        int g = k * 256 + tid;
        int i = 32 + (g >> 6), c = g & 63;
        *(f32x4*)(W_s + (i & 31) * 256 + ((c ^ (i & 7)) << 2)) =
            *(const f32x4*)(Wn + 8192 + g * 4);
    }
    __syncthreads();
    if (w >= 2) {
#pragma unroll
        for (int e = 0; e < 16; ++e)
            w_regs[e] = *(const f32x4*)(W_s + (i_ & 31) * 256 + (((e * 4 + oq) ^ (i_ & 7)) << 2));
    }
    __syncthreads();

    s16x8 ones;
#pragma unroll
    for (int j = 0; j < 8; ++j) ones[j] = (short)0x3F80;  // bf16 1.0

    const int col = l & 15;
    const int kg  = l >> 4;

    for (int t = 0; t < QPB; ++t) {
        const int q = qg * QPB + t;        // quad index; positions q*4..q*4+3

        // ---- stage inp quad (16 KB) coalesced -> LDS, swizzled chunks
#pragma unroll
        for (int k = 0; k < 4; ++k) {
            int g = k * 256 + tid;         // chunk 0..1023; p = g>>8, c = g&255
            int p = g >> 8, c = g & 255;
            *(f32x4*)(inp_s + p * 1024 + ((c ^ ((c >> 3) & 7)) << 2)) =
                *(const f32x4*)(inp + (size_t)q * 4096 + g * 4);
        }
        __syncthreads();

        // ---- einsum: res[p][i_][oq*4+d] = sum_e inp[p][i_][e] * W[i_,e,oq*4+d]
#pragma unroll
        for (int p = 0; p < 4; ++p) {
            f32x4 a[4];
#pragma unroll
            for (int eq = 0; eq < 4; ++eq) {
                int c = i_ * 4 + eq;
                a[eq] = *(const f32x4*)(inp_s + p * 1024 + ((c ^ ((i_ >> 1) & 7)) << 2));
            }
            f32x4 acc = (f32x4)0.0f;
#pragma unroll
            for (int e = 0; e < 16; ++e)
                acc += a[e >> 2][e & 3] * w_regs[e];
            // write 4 bf16 to res_s [p][o][i] (chunk = i>>3 XOR (o&7), elem i&7)
#pragma unroll
            for (int d = 0; d < 4; ++d) {
                int o = oq * 4 + d;
                __hip_bfloat16 b = __float2bfloat16(acc[d]);
                int byte = p * 2048 + o * 128 + (((i_ >> 3) ^ (o & 7)) << 4) + (i_ & 7) * 2;
                *(unsigned short*)(res_s + byte) = *(unsigned short*)&b;
            }
        }
        __syncthreads();

        // ---- phase B: wave w handles pos = q*4 + w
        // fragment: fr_c[j] = res[i = kg*8 + j + 32c][col]  (one b128 per half)
        s16x8 fr0 = *(const s16x8*)(res_s + w * 2048 + col * 128 + (((kg + 0) ^ (col & 7)) << 4));
        s16x8 fr1 = *(const s16x8*)(res_s + w * 2048 + col * 128 + (((kg + 4) ^ (col & 7)) << 4));

        f32x4 G  = (f32x4)0.0f;
        f32x4 C2 = (f32x4)0.0f;
        G  = __builtin_amdgcn_mfma_f32_16x16x32_bf16(fr0, fr0, G, 0, 0, 0);
        G  = __builtin_amdgcn_mfma_f32_16x16x32_bf16(fr1, fr1, G, 0, 0, 0);
        C2 = __builtin_amdgcn_mfma_f32_16x16x32_bf16(ones, fr0, C2, 0, 0, 0);
        C2 = __builtin_amdgcn_mfma_f32_16x16x32_bf16(ones, fr1, C2, 0, 0, 0);
        // G reg rr holds G[row = kg*4+rr][col]; C2: column sums (rows equal)

        float s = C2[0] * (1.0f / 64.0f);   // s0[col]

#pragma unroll
        for (int it = 0; it < 2; ++it) {
            float sn = s * s;
            sn += __shfl_xor(sn, 1);
            sn += __shfl_xor(sn, 2);
            sn += __shfl_xor(sn, 4);
            sn += __shfl_xor(sn, 8);
            float scale = sqrtf(sn) / (1.0f + sn);
            float v = scale * s;                // v[col] = squash(s)[col]
            float v0 = __shfl(v, kg * 4 + 0);
            float v1 = __shfl(v, kg * 4 + 1);
            float v2 = __shfl(v, kg * 4 + 2);
            float v3 = __shfl(v, kg * 4 + 3);
            float acc = G[0] * v0 + G[1] * v1 + G[2] * v2 + G[3] * v3;
            acc += __shfl_xor(acc, 16);
            acc += __shfl_xor(acc, 32);
            s += acc;
        }

        float sn = s * s;
        sn += __shfl_xor(sn, 1);
        sn += __shfl_xor(sn, 2);
        sn += __shfl_xor(sn, 4);
        sn += __shfl_xor(sn, 8);
        float scale = sqrtf(sn) / (1.0f + sn);
        float v = scale * s;

        if (l < 16)
            out[((size_t)(q * 4 + w) * 10 + n) * 16 + col] = v;
    }
}

extern "C" void kernel_launch(void* const* d_in, const int* in_sizes, int n_in,
                              void* d_out, int out_size, void* d_ws, size_t ws_size,
                              hipStream_t stream) {
    const float* inp = (const float*)d_in[0];   // [3136][64][16]
    const float* W   = (const float*)d_in[1];   // [10][64][16][16]
    float* out = (float*)d_out;                 // [3136][10][16]

    // 10 n * 98 quad-groups (98*8 quads = 784 = 3136/4)
    dim3 grid(980), block(256);
    hipLaunchKernelGGL(caps_kernel, grid, block, 32768, stream, inp, W, out);
}

// Round 4
// 34.276 us; speedup vs baseline: 3.3729x; 1.3172x over previous
//
#include <hip/hip_runtime.h>
#include <hip/hip_bf16.h>

typedef __attribute__((ext_vector_type(4))) float f32x4;
typedef __attribute__((ext_vector_type(8))) short s16x8;

#define GLOBAL_AS __attribute__((address_space(1)))
#define LDS_AS    __attribute__((address_space(3)))

#define QPB 8

// B*R*C = 3136 positions, n_caps=10, n_in=64, d_in=16, caps_dim=16.
// inputs: [3136][64][16] f32, W: [10][64][16][16] f32, out: [3136][10][16] f32.
// Gram-space routing per (pos,n): G = R^T R (MFMA), s0 = (1/64) R^T 1,
// s += G*squash(s) x2, out = squash(s).

template<int CTRL>
__device__ __forceinline__ float dpp_add(float x) {
    int v = __builtin_amdgcn_update_dpp(0, __float_as_int(x), CTRL, 0xF, 0xF, true);
    return x + __int_as_float(v);
}

// stage one inp quad (4 pos x 64 i x 16 e f32 = 16 KB) via global_load_lds,
// linear LDS dest + inverse-swizzled global source (swizzle: chunk low3 ^= bits[5:3])
__device__ __forceinline__ void stage_inp(const float* gq, char* ldst, int tid) {
#pragma unroll
    for (int k = 0; k < 4; ++k) {
        int d  = k * 256 + tid;       // dest chunk (16B units), linear
        int p  = d >> 8;
        int cd = d & 255;
        int c  = cd ^ ((cd >> 3) & 7);  // self-inverse
        __builtin_amdgcn_global_load_lds(
            (const GLOBAL_AS unsigned int*)(gq + (p * 256 + c) * 4),
            (LDS_AS unsigned int*)(ldst + d * 16), 16, 0, 0);
    }
}

__global__ __launch_bounds__(256, 4) void caps_kernel(
    const float* __restrict__ inp,
    const float* __restrict__ W,
    float* __restrict__ out)
{
    const int tid = threadIdx.x;
    const int w   = tid >> 6;
    const int l   = tid & 63;
    const int n   = blockIdx.x / 98;
    const int qg  = blockIdx.x % 98;
    const int q0  = qg * QPB;

    extern __shared__ __align__(16) char smem[];
    float* inp0  = (float*)smem;             // [0,16K)
    float* inp1  = (float*)(smem + 16384);   // [16K,32K)
    char*  res_s = smem + 32768;             // [32K,40K)
    float* Wq    = inp0;                     // W quarter buffer (prologue only)

    const int i4 = l >> 2;          // i within 16-block (0..15)
    const int oq = l & 3;           // o-quad
    const int i_ = w * 16 + i4;     // einsum input capsule (0..63)

    // issue inp stage for quad q0 early (dest inp1; disjoint from Wq=inp0)
    stage_inp(inp + (size_t)q0 * 4096, (char*)inp1, tid);

    // ---- W prologue: 4 quarters (16 i-rows = 16KB each) into Wq; wave k gathers
    const float* Wn = W + (size_t)n * 16384;
    f32x4 w_regs[16];   // W[i_, e, oq*4..+3] for e=0..15
    for (int k = 0; k < 4; ++k) {
#pragma unroll
        for (int k2 = 0; k2 < 4; ++k2) {
            int d  = k2 * 256 + tid;    // chunk in quarter (16B units)
            int ir = d >> 6;            // row 0..15
            int cd = d & 63;
            int c  = cd ^ (ir & 7);     // inverse swizzle
            __builtin_amdgcn_global_load_lds(
                (const GLOBAL_AS unsigned int*)(Wn + (k * 1024 + ir * 64 + c) * 4),
                (LDS_AS unsigned int*)((char*)Wq + d * 16), 16, 0, 0);
        }
        __syncthreads();
        if (w == k) {
#pragma unroll
            for (int e = 0; e < 16; ++e)
                w_regs[e] = *(const f32x4*)(Wq + i4 * 256 + (((e * 4 + oq) ^ (i4 & 7)) << 2));
        }
        __syncthreads();
    }

    const int col = l & 15;
    const int kg  = l >> 4;

    s16x8 ones;
#pragma unroll
    for (int j = 0; j < 8; ++j) ones[j] = (short)0x3F80;  // bf16 1.0

#pragma unroll 2
    for (int t = 0; t < QPB; ++t) {
        const int q = q0 + t;
        const float* buf = (t & 1) ? inp0 : inp1;          // staged last iter
        if (t + 1 < QPB)
            stage_inp(inp + (size_t)(q + 1) * 4096,
                      (t & 1) ? (char*)inp1 : (char*)inp0, tid);

        // ---- einsum: res[p][i_][o] = sum_e inp[p][i_][e] * W[i_,e,o]
#pragma unroll
        for (int p = 0; p < 4; ++p) {
            f32x4 a[4];
#pragma unroll
            for (int eq = 0; eq < 4; ++eq) {
                int c = i_ * 4 + eq;
                a[eq] = *(const f32x4*)(buf + p * 1024 + ((c ^ ((i_ >> 1) & 7)) << 2));
            }
            f32x4 acc = (f32x4)0.0f;
#pragma unroll
            for (int e = 0; e < 16; ++e)
                acc += a[e >> 2][e & 3] * w_regs[e];
            // res layout [p][o][i] bf16, chunk-XOR swizzled (verified R3)
#pragma unroll
            for (int d = 0; d < 4; ++d) {
                int o = oq * 4 + d;
                __hip_bfloat16 b = __float2bfloat16(acc[d]);
                int byte = p * 2048 + o * 128 + (((i_ >> 3) ^ (o & 7)) << 4) + (i_ & 7) * 2;
                *(unsigned short*)(res_s + byte) = *(unsigned short*)&b;
            }
        }

        // barrier A: drain LDS only — stage loads stay in flight (counted-vmcnt idea)
        asm volatile("s_waitcnt lgkmcnt(0)" ::: "memory");
        __builtin_amdgcn_s_barrier();
        asm volatile("" ::: "memory");
        __builtin_amdgcn_sched_barrier(0);

        // ---- phase B: wave w handles pos q*4+w
        s16x8 fr0 = *(const s16x8*)(res_s + w * 2048 + col * 128 + (((kg + 0) ^ (col & 7)) << 4));
        s16x8 fr1 = *(const s16x8*)(res_s + w * 2048 + col * 128 + (((kg + 4) ^ (col & 7)) << 4));

        f32x4 G  = (f32x4)0.0f;
        f32x4 C2 = (f32x4)0.0f;
        G  = __builtin_amdgcn_mfma_f32_16x16x32_bf16(fr0, fr0, G, 0, 0, 0);
        G  = __builtin_amdgcn_mfma_f32_16x16x32_bf16(fr1, fr1, G, 0, 0, 0);
        C2 = __builtin_amdgcn_mfma_f32_16x16x32_bf16(ones, fr0, C2, 0, 0, 0);
        C2 = __builtin_amdgcn_mfma_f32_16x16x32_bf16(ones, fr1, C2, 0, 0, 0);
        // G reg rr = G[kg*4+rr][col]; C2: column sums (all rows equal)

        float s = C2[0] * (1.0f / 64.0f);   // s0[col]

#pragma unroll
        for (int it = 0; it < 2; ++it) {
            float sn = s * s;                // 16-lane sum via DPP (VALU only)
            sn = dpp_add<0xB1>(sn);          // quad_perm xor1
            sn = dpp_add<0x4E>(sn);          // quad_perm xor2
            sn = dpp_add<0x124>(sn);         // row_ror:4
            sn = dpp_add<0x128>(sn);         // row_ror:8
            float scale = sqrtf(sn) / (1.0f + sn);
            float v = scale * s;
            float v0 = __shfl(v, kg * 4 + 0);
            float v1 = __shfl(v, kg * 4 + 1);
            float v2 = __shfl(v, kg * 4 + 2);
            float v3 = __shfl(v, kg * 4 + 3);
            float acc2 = G[0] * v0 + G[1] * v1 + G[2] * v2 + G[3] * v3;
            acc2 += __shfl_xor(acc2, 16);
            acc2 += __shfl_xor(acc2, 32);
            s += acc2;
        }

        float sn = s * s;
        sn = dpp_add<0xB1>(sn);
        sn = dpp_add<0x4E>(sn);
        sn = dpp_add<0x124>(sn);
        sn = dpp_add<0x128>(sn);
        float scale = sqrtf(sn) / (1.0f + sn);
        float v = scale * s;

        // barrier B: stage(t+1) must be landed before anyone reads it next iter
        asm volatile("s_waitcnt vmcnt(0)" ::: "memory");
        __builtin_amdgcn_s_barrier();
        asm volatile("" ::: "memory");
        __builtin_amdgcn_sched_barrier(0);

        // out store after the barrier: its completion is waited one iter later
        if (l < 16)
            out[((size_t)(q * 4 + w) * 10 + n) * 16 + col] = v;
    }
}

extern "C" void kernel_launch(void* const* d_in, const int* in_sizes, int n_in,
                              void* d_out, int out_size, void* d_ws, size_t ws_size,
                              hipStream_t stream) {
    const float* inp = (const float*)d_in[0];   // [3136][64][16]
    const float* W   = (const float*)d_in[1];   // [10][64][16][16]
    float* out = (float*)d_out;                 // [3136][10][16]

    // 10 n * 98 quad-groups (98*8 quads = 784 = 3136/4); 40 KB dyn LDS -> 4 blocks/CU
    dim3 grid(980), block(256);
    hipLaunchKernelGGL(caps_kernel, grid, block, 40960, stream, inp, W, out);
}